// Round 1
// baseline (643.341 us; speedup 1.0000x reference)
//
#include <hip/hip_runtime.h>

// Problem constants (BS=1)
#define CAMS   6
#define NQ     6400
#define EMBED  256
#define HEADS  8
#define LEVELS 4
#define POINTS 8
#define DEPTH  4
#define DH     32
#define FLEN   14960
#define MV     (FLEN * CAMS)   // 89760 rows for v-projection

// Level geometry (hardcoded from SHAPES)
__constant__ int c_LW[4] = {176, 88, 44, 22};
__constant__ int c_LH[4] = {64, 32, 16, 8};
__constant__ int c_LS[4] = {0, 11264, 14080, 14784};

// ---------------------------------------------------------------------------
// bev_mask format detection: flag=1 -> raw bool bytes (u8), flag=0 -> int32.
// Under int32 with values {0,1}, every 32-bit word has bytes 1..3 == 0.
// Under packed u8 at ~10% density, some word certainly has a high byte set.
// Reads only the first 38400 words (153600 B) which is safe in both formats.
// ---------------------------------------------------------------------------
__global__ void detect_mask_fmt(const unsigned* __restrict__ bm, int* __restrict__ flag) {
    __shared__ int found;
    if (threadIdx.x == 0) found = 0;
    __syncthreads();
    int local = 0;
    for (int i = threadIdx.x; i < (CAMS * NQ * DEPTH) / 4; i += 256) {
        if (bm[i] & 0xFFFFFF00u) { local = 1; break; }
    }
    if (local) atomicOr(&found, 1);
    __syncthreads();
    if (threadIdx.x == 0) *flag = found ? 1 : 0;
}

// active[cam*NQ+q] = any_d bev_mask[cam,0,q,d]; invcnt[q] = 1/max(#active cams,1)
__global__ void mask_kernel(const void* __restrict__ bm, const int* __restrict__ flag,
                            int* __restrict__ active, float* __restrict__ invcnt) {
    int q = blockIdx.x * blockDim.x + threadIdx.x;
    if (q >= NQ) return;
    int fmt = *flag;
    int cnt = 0;
    for (int cam = 0; cam < CAMS; ++cam) {
        int a;
        if (fmt == 1) {
            // 4 bool bytes in one word
            unsigned w = ((const unsigned*)bm)[cam * NQ + q];
            a = (w != 0u);
        } else {
            int4 v = ((const int4*)bm)[cam * NQ + q];
            a = ((v.x | v.y | v.z | v.w) != 0);
        }
        active[cam * NQ + q] = a;
        cnt += a;
    }
    invcnt[q] = 1.0f / (float)(cnt > 0 ? cnt : 1);
}

// ---------------------------------------------------------------------------
// fp32 tiled GEMM: C[M,N] = op(A)[M,256] @ W[256,N] + bias (+ extras)
// MODE 0: plain A            (v-projection)
// MODE 1: A = A + A2         (q = query + query_pos)
// MODE 2: A = A * A2[row], C += resid[row,col]   (final out-proj w/ residual)
// BM=BN=64, BK=16, 256 threads, 4x4 per thread.
// ---------------------------------------------------------------------------
template <int MODE>
__launch_bounds__(256)
__global__ void gemm_kernel(const float* __restrict__ A,
                            const float* __restrict__ A2,
                            const float* __restrict__ W, int ldw,
                            const float* __restrict__ bias,
                            const float* __restrict__ resid,
                            float* __restrict__ C, int ldc,
                            int M) {
    __shared__ float sA[16][65];  // [k][m], +1 pad to break write conflicts
    __shared__ float sB[16][64];  // [k][n]
    const int t = threadIdx.x;
    const int tx = t & 15, ty = t >> 4;
    const int row0 = blockIdx.x * 64;
    const int n0 = blockIdx.y * 64;
    float acc[4][4] = {};

    const int arow = t >> 2;        // 0..63
    const int akq  = (t & 3) * 4;   // 0,4,8,12
    const int bk   = t >> 4;        // 0..15
    const int bn   = (t & 15) * 4;  // 0..60

    for (int k0 = 0; k0 < 256; k0 += 16) {
        float4 a4;
        const int grow = row0 + arow;
        if (grow < M) {
            a4 = *(const float4*)(A + (size_t)grow * 256 + k0 + akq);
            if (MODE == 1) {
                float4 b4 = *(const float4*)(A2 + (size_t)grow * 256 + k0 + akq);
                a4.x += b4.x; a4.y += b4.y; a4.z += b4.z; a4.w += b4.w;
            } else if (MODE == 2) {
                float s = A2[grow];
                a4.x *= s; a4.y *= s; a4.z *= s; a4.w *= s;
            }
        } else {
            a4 = make_float4(0.f, 0.f, 0.f, 0.f);
        }
        sA[akq + 0][arow] = a4.x;
        sA[akq + 1][arow] = a4.y;
        sA[akq + 2][arow] = a4.z;
        sA[akq + 3][arow] = a4.w;

        *(float4*)&sB[bk][bn] = *(const float4*)(W + (size_t)(k0 + bk) * ldw + n0 + bn);
        __syncthreads();

        #pragma unroll
        for (int k = 0; k < 16; ++k) {
            float a[4], b[4];
            #pragma unroll
            for (int i = 0; i < 4; ++i) a[i] = sA[k][ty * 4 + i];
            #pragma unroll
            for (int j = 0; j < 4; ++j) b[j] = sB[k][tx * 4 + j];
            #pragma unroll
            for (int i = 0; i < 4; ++i)
                #pragma unroll
                for (int j = 0; j < 4; ++j)
                    acc[i][j] += a[i] * b[j];
        }
        __syncthreads();
    }

    #pragma unroll
    for (int i = 0; i < 4; ++i) {
        const int row = row0 + ty * 4 + i;
        if (row >= M) continue;
        #pragma unroll
        for (int j = 0; j < 4; ++j) {
            const int col = n0 + tx * 4 + j;
            float v = acc[i][j] + bias[col];
            if (MODE == 2) v += resid[(size_t)row * 256 + col];
            C[(size_t)row * ldc + col] = v;
        }
    }
}

// ---------------------------------------------------------------------------
// softmax over 32 (l,p) entries per (q,h); in-place on logits buffer (NQ,256)
// 8 groups of 32 lanes per 256-thread block.
// ---------------------------------------------------------------------------
__global__ void softmax_kernel(float* __restrict__ aw) {
    const int t = threadIdx.x;
    const int g = blockIdx.x * 8 + (t >> 5);  // (q*8 + h)
    const int j = t & 31;
    float v = aw[g * 32 + j];
    float m = v;
    for (int off = 16; off > 0; off >>= 1) m = fmaxf(m, __shfl_xor(m, off, 32));
    float e = expf(v - m);
    float s = e;
    for (int off = 16; off > 0; off >>= 1) s += __shfl_xor(s, off, 32);
    aw[g * 32 + j] = e / s;
}

// ---------------------------------------------------------------------------
// Deformable sampling. One block (256 threads) per query; loops over active
// cams, accumulating slots[q,256] in registers (no atomics).
// Phase 1: thread t=(h,l,p) computes 4 corner addresses + (bilinear*aw)
//          weights into LDS.  Phase 2: thread t=(h,ch) gathers/accumulates.
// v layout matches value: row = pix*CAMS+cam, 256 channels (h*32+ch).
// ---------------------------------------------------------------------------
__launch_bounds__(256)
__global__ void sample_kernel(const float* __restrict__ v,
                              const float* __restrict__ off_ws,
                              const float* __restrict__ aw_ws,
                              const float* __restrict__ rp,      // (CAMS,NQ,DEPTH,2)
                              const int* __restrict__ active,
                              float* __restrict__ slots) {
    const int q = blockIdx.x;
    const int t = threadIdx.x;
    const int h = t >> 5;
    const int l = (t >> 3) & 3;
    const int p = t & 7;
    const int d = p & 3;          // POINTS=(pa=2)*(DEPTH=4): depth = p%4
    const int ch = t & 31;

    // cam-independent per-(h,l,p) values
    const float offx = off_ws[q * 512 + h * 64 + l * 16 + p * 2 + 0];
    const float offy = off_ws[q * 512 + h * 64 + l * 16 + p * 2 + 1];
    const float aw   = aw_ws[q * 256 + h * 32 + l * 8 + p];
    const int Wl = c_LW[l], Hl = c_LH[l], St = c_LS[l];

    __shared__ int   s_addr[256][4];
    __shared__ float s_w[256][4];

    float acc = 0.f;
    for (int cam = 0; cam < CAMS; ++cam) {
        if (!active[cam * NQ + q]) continue;  // block-uniform branch

        const float refx = rp[cam * (NQ * DEPTH * 2) + q * 8 + d * 2 + 0];
        const float refy = rp[cam * (NQ * DEPTH * 2) + q * 8 + d * 2 + 1];
        const float x = refx * (float)Wl + offx - 0.5f;
        const float y = refy * (float)Hl + offy - 0.5f;
        const float x0f = floorf(x), y0f = floorf(y);
        const int x0 = (int)x0f, y0 = (int)y0f;
        const float fx = x - x0f, fy = y - y0f;
        const float w00 = (1.f - fx) * (1.f - fy) * aw;
        const float w10 = fx * (1.f - fy) * aw;
        const float w01 = (1.f - fx) * fy * aw;
        const float w11 = fx * fy * aw;

        #pragma unroll
        for (int c = 0; c < 4; ++c) {
            const int cx = x0 + (c & 1);
            const int cy = y0 + (c >> 1);
            const float w = (c == 0) ? w00 : (c == 1) ? w10 : (c == 2) ? w01 : w11;
            const bool valid = (cx >= 0) & (cx < Wl) & (cy >= 0) & (cy < Hl);
            const int idx = valid ? (St + cy * Wl + cx) : 0;
            s_addr[t][c] = (idx * CAMS + cam) * 256 + h * 32;
            s_w[t][c] = valid ? w : 0.f;
        }
        __syncthreads();

        const int e0 = h * 32;
        #pragma unroll 4
        for (int j = 0; j < 32; ++j) {
            const int e = e0 + j;
            #pragma unroll
            for (int c = 0; c < 4; ++c) {
                acc += s_w[e][c] * v[s_addr[e][c] + ch];
            }
        }
        __syncthreads();
    }
    slots[q * 256 + t] = acc;
}

// ---------------------------------------------------------------------------
extern "C" void kernel_launch(void* const* d_in, const int* in_sizes, int n_in,
                              void* d_out, int out_size, void* d_ws, size_t ws_size,
                              hipStream_t stream) {
    const float* query     = (const float*)d_in[0];
    // d_in[1] = key (unused by reference)
    const float* value     = (const float*)d_in[2];
    const float* query_pos = (const float*)d_in[3];
    const float* refpts    = (const float*)d_in[4];
    const void*  bev_mask  = d_in[5];
    const float* Wv   = (const float*)d_in[8];
    const float* bv   = (const float*)d_in[9];
    const float* Wso  = (const float*)d_in[10];
    const float* bso  = (const float*)d_in[11];
    const float* Waw  = (const float*)d_in[12];
    const float* baw  = (const float*)d_in[13];
    const float* Wout = (const float*)d_in[14];
    const float* bout = (const float*)d_in[15];
    float* out = (float*)d_out;

    // Workspace layout (floats). Total ~29.6M floats = ~118.3 MB.
    float* fws     = (float*)d_ws;
    float* v_ws    = fws;                       // MV*256      = 22,978,560
    float* off_ws  = v_ws + (size_t)MV * 256;   // NQ*512      =  3,276,800
    float* aw_ws   = off_ws + (size_t)NQ * 512; // NQ*256      =  1,638,400
    float* slots   = aw_ws + (size_t)NQ * 256;  // NQ*256      =  1,638,400
    float* invcnt  = slots + (size_t)NQ * 256;  // NQ
    int*   active  = (int*)(invcnt + NQ);       // CAMS*NQ
    int*   flag    = active + (size_t)CAMS * NQ;

    // 1) bev_mask format + per-(cam,q) active + 1/count
    hipLaunchKernelGGL(detect_mask_fmt, dim3(1), dim3(256), 0, stream,
                       (const unsigned*)bev_mask, flag);
    hipLaunchKernelGGL(mask_kernel, dim3((NQ + 255) / 256), dim3(256), 0, stream,
                       bev_mask, flag, active, invcnt);

    // 2) q-projections (cam-independent): offsets (N=512) and aw logits (N=256)
    hipLaunchKernelGGL((gemm_kernel<1>), dim3(NQ / 64, 512 / 64), dim3(256), 0, stream,
                       query, query_pos, Wso, 512, bso, nullptr, off_ws, 512, NQ);
    hipLaunchKernelGGL((gemm_kernel<1>), dim3(NQ / 64, 256 / 64), dim3(256), 0, stream,
                       query, query_pos, Waw, 256, baw, nullptr, aw_ws, 256, NQ);
    hipLaunchKernelGGL(softmax_kernel, dim3(NQ * HEADS / 8), dim3(256), 0, stream, aw_ws);

    // 3) v-projection: (89760,256)@(256,256), rows in (pix,cam) order
    hipLaunchKernelGGL((gemm_kernel<0>), dim3((MV + 63) / 64, 256 / 64), dim3(256), 0, stream,
                       value, nullptr, Wv, 256, bv, nullptr, v_ws, 256, MV);

    // 4) deformable sampling, accumulate over active cams -> slots (unscaled)
    hipLaunchKernelGGL(sample_kernel, dim3(NQ), dim3(256), 0, stream,
                       v_ws, off_ws, aw_ws, refpts, active, slots);

    // 5) out = (slots/count) @ Wout + bout + query
    hipLaunchKernelGGL((gemm_kernel<2>), dim3(NQ / 64, 256 / 64), dim3(256), 0, stream,
                       slots, invcnt, Wout, 256, bout, query, out, 256, NQ);
}

// Round 2
// 587.273 us; speedup vs baseline: 1.0955x; 1.0955x over previous
//
#include <hip/hip_runtime.h>
#include <hip/hip_bf16.h>

// Problem constants (BS=1)
#define CAMS   6
#define NQ     6400
#define EMBED  256
#define HEADS  8
#define LEVELS 4
#define POINTS 8
#define DEPTH  4
#define DH     32
#define FLEN   14960
#define MV     (FLEN * CAMS)   // 89760 rows for v-projection

__constant__ int c_LW[4] = {176, 88, 44, 22};
__constant__ int c_LH[4] = {64, 32, 16, 8};
__constant__ int c_LS[4] = {0, 11264, 14080, 14784};

typedef __bf16 bf16x8 __attribute__((ext_vector_type(8)));
typedef float  f32x4  __attribute__((ext_vector_type(4)));

__device__ __forceinline__ ushort f2bf(float x) {
    __hip_bfloat16 h = __float2bfloat16(x);
    return *(ushort*)&h;
}
__device__ __forceinline__ float bflo(unsigned u) { return __uint_as_float(u << 16); }
__device__ __forceinline__ float bfhi(unsigned u) { return __uint_as_float(u & 0xffff0000u); }

// ---------------------------------------------------------------------------
// bev_mask format detection (int32 vs raw bool bytes) — same as R1 (worked).
// ---------------------------------------------------------------------------
__global__ void detect_mask_fmt(const unsigned* __restrict__ bm, int* __restrict__ flag) {
    __shared__ int found;
    if (threadIdx.x == 0) found = 0;
    __syncthreads();
    int local = 0;
    for (int i = threadIdx.x; i < (CAMS * NQ * DEPTH) / 4; i += 256) {
        if (bm[i] & 0xFFFFFF00u) { local = 1; break; }
    }
    if (local) atomicOr(&found, 1);
    __syncthreads();
    if (threadIdx.x == 0) *flag = found ? 1 : 0;
}

__global__ void mask_kernel(const void* __restrict__ bm, const int* __restrict__ flag,
                            int* __restrict__ active, float* __restrict__ invcnt) {
    int q = blockIdx.x * blockDim.x + threadIdx.x;
    if (q >= NQ) return;
    int fmt = *flag;
    int cnt = 0;
    for (int cam = 0; cam < CAMS; ++cam) {
        int a;
        if (fmt == 1) {
            unsigned w = ((const unsigned*)bm)[cam * NQ + q];
            a = (w != 0u);
        } else {
            int4 v = ((const int4*)bm)[cam * NQ + q];
            a = ((v.x | v.y | v.z | v.w) != 0);
        }
        active[cam * NQ + q] = a;
        cnt += a;
    }
    invcnt[q] = 1.0f / (float)(cnt > 0 ? cnt : 1);
}

// ---------------------------------------------------------------------------
// bf16 MFMA GEMM: C[M,N] = op(A_fp32)[M,256] (bf16-cast) @ W_fp32[256,N] + bias
// Block tile 128x128, 256 threads = 4 waves (2x2 of 64x64), BK=32, K=256.
// MODE 0: plain A                       (v-projection, OUT_BF16=1)
// MODE 1: A = A + A2                    (q = query + query_pos)
// MODE 2: A = A * A2[row]; C += resid   (final out-proj w/ residual)
// LDS tiles stored [m][k] / [n][k], row stride 40 bf16 (80 B):
//   b128 frag reads land 2-way max (free); 16B-aligned.
// ---------------------------------------------------------------------------
#define LSTRIDE 40

template <int MODE, int OUT_BF16>
__launch_bounds__(256)
__global__ void gemm_mfma(const float* __restrict__ A,
                          const float* __restrict__ A2,
                          const float* __restrict__ W, int ldw,
                          const float* __restrict__ bias,
                          const float* __restrict__ resid,
                          void* __restrict__ Cout, int ldc, int M) {
    __shared__ ushort sA[128 * LSTRIDE];
    __shared__ ushort sB[128 * LSTRIDE];
    const int t = threadIdx.x;
    const int wave = t >> 6;
    const int lane = t & 63;
    const int wm = wave & 1, wn = wave >> 1;
    const int lane15 = lane & 15;
    const int laneq = lane >> 4;
    const int row0 = blockIdx.x * 128;
    const int col0 = blockIdx.y * 128;

    f32x4 acc[4][4] = {};   // [mi][nj], each 4 rows

    // A staging: thread -> (m = t>>3 [+32*pass], k4 = (t&7)*4)
    const int a_m = t >> 3;
    const int a_k = (t & 7) * 4;
    // B staging: thread -> (n = t&127, k = (t>>7)*4 [+8*pass]); loads 4 consecutive k
    const int b_n = t & 127;
    const int b_k = (t >> 7) * 4;

    for (int k0 = 0; k0 < 256; k0 += 32) {
        // ---- stage A (fp32 -> bf16), LDS layout [m][k] ----
        #pragma unroll
        for (int p = 0; p < 4; ++p) {
            const int m = a_m + p * 32;
            int gm = row0 + m;
            if (gm >= M) gm = M - 1;   // clamp; stores are guarded
            float4 a4 = *(const float4*)(A + (size_t)gm * 256 + k0 + a_k);
            if (MODE == 1) {
                float4 b4 = *(const float4*)(A2 + (size_t)gm * 256 + k0 + a_k);
                a4.x += b4.x; a4.y += b4.y; a4.z += b4.z; a4.w += b4.w;
            } else if (MODE == 2) {
                const float s = A2[gm];
                a4.x *= s; a4.y *= s; a4.z *= s; a4.w *= s;
            }
            ushort4 u = make_ushort4(f2bf(a4.x), f2bf(a4.y), f2bf(a4.z), f2bf(a4.w));
            *(ushort4*)(&sA[m * LSTRIDE + a_k]) = u;
        }
        // ---- stage B (W[k][n] -> LDS [n][k], fp32 -> bf16) ----
        #pragma unroll
        for (int p = 0; p < 4; ++p) {
            const int k = b_k + p * 8;
            const float* wp = W + (size_t)(k0 + k) * ldw + col0 + b_n;
            const float w0 = wp[0];
            const float w1 = wp[ldw];
            const float w2 = wp[2 * ldw];
            const float w3 = wp[3 * ldw];
            ushort4 u = make_ushort4(f2bf(w0), f2bf(w1), f2bf(w2), f2bf(w3));
            *(ushort4*)(&sB[b_n * LSTRIDE + k]) = u;
        }
        __syncthreads();

        // ---- fragments + 16 MFMAs ----
        bf16x8 af[4], bfr[4];
        #pragma unroll
        for (int i = 0; i < 4; ++i) {
            const int m = wm * 64 + i * 16 + lane15;
            af[i] = *(const bf16x8*)(&sA[m * LSTRIDE + laneq * 8]);
            const int n = wn * 64 + i * 16 + lane15;
            bfr[i] = *(const bf16x8*)(&sB[n * LSTRIDE + laneq * 8]);
        }
        #pragma unroll
        for (int i = 0; i < 4; ++i)
            #pragma unroll
            for (int j = 0; j < 4; ++j)
                acc[i][j] = __builtin_amdgcn_mfma_f32_16x16x32_bf16(af[i], bfr[j], acc[i][j], 0, 0, 0);
        __syncthreads();
    }

    // ---- epilogue: D[row = quad*4+r][col = lane&15] ----
    #pragma unroll
    for (int j = 0; j < 4; ++j) {
        const int col = col0 + wn * 64 + j * 16 + lane15;
        const float bcol = bias[col];
        #pragma unroll
        for (int i = 0; i < 4; ++i) {
            #pragma unroll
            for (int r = 0; r < 4; ++r) {
                const int row = row0 + wm * 64 + i * 16 + laneq * 4 + r;
                if (row < M) {
                    float v = acc[i][j][r] + bcol;
                    if (MODE == 2) v += resid[(size_t)row * 256 + col];
                    if (OUT_BF16)
                        ((ushort*)Cout)[(size_t)row * ldc + col] = f2bf(v);
                    else
                        ((float*)Cout)[(size_t)row * ldc + col] = v;
                }
            }
        }
    }
}

// ---------------------------------------------------------------------------
// softmax over 32 (l,p) entries per (q,h), in-place, fp32
// ---------------------------------------------------------------------------
__global__ void softmax_kernel(float* __restrict__ aw) {
    const int t = threadIdx.x;
    const int g = blockIdx.x * 8 + (t >> 5);
    const int j = t & 31;
    float v = aw[g * 32 + j];
    float m = v;
    for (int off = 16; off > 0; off >>= 1) m = fmaxf(m, __shfl_xor(m, off, 32));
    float e = expf(v - m);
    float s = e;
    for (int off = 16; off > 0; off >>= 1) s += __shfl_xor(s, off, 32);
    aw[g * 32 + j] = e / s;
}

// ---------------------------------------------------------------------------
// Deformable sampling, v in bf16. One block per query, loop over active cams.
// Phase 1: thread t=(h,l,p) computes 4 corners -> (addr, weight) int2 in LDS.
// Phase 2: thread t=(h, ch8=(idx&3)*8, e8=idx>>2) gathers uint4 (8 bf16 ch)
//          for 4 entries x 4 corners. After the cam loop: butterfly-reduce
//          over the 8 entry-groups (lanes differing in e8) and store.
// ---------------------------------------------------------------------------
__launch_bounds__(256)
__global__ void sample_kernel(const ushort* __restrict__ v,
                              const float* __restrict__ off_ws,
                              const float* __restrict__ aw_ws,
                              const float* __restrict__ rp,      // (CAMS,NQ,DEPTH,2)
                              const int* __restrict__ active,
                              float* __restrict__ slots) {
    const int q = blockIdx.x;
    const int t = threadIdx.x;
    // phase-1 role: t = h*32 + l*8 + p
    const int h = t >> 5;
    const int l = (t >> 3) & 3;
    const int p = t & 7;
    const int d = p & 3;
    // phase-2 role
    const int idx = t & 31;
    const int ch8 = (idx & 3) * 8;
    const int e8  = idx >> 2;

    const float offx = off_ws[q * 512 + t * 2 + 0];
    const float offy = off_ws[q * 512 + t * 2 + 1];
    const float aw   = aw_ws[q * 256 + t];
    const int Wl = c_LW[l], Hl = c_LH[l], St = c_LS[l];

    __shared__ int2 s_aw[256][4];

    float acc[8] = {};

    for (int cam = 0; cam < CAMS; ++cam) {
        if (!active[cam * NQ + q]) continue;   // block-uniform

        const float refx = rp[cam * (NQ * 8) + q * 8 + d * 2 + 0];
        const float refy = rp[cam * (NQ * 8) + q * 8 + d * 2 + 1];
        const float x = fmaf(refx, (float)Wl, offx) - 0.5f;
        const float y = fmaf(refy, (float)Hl, offy) - 0.5f;
        const float x0f = floorf(x), y0f = floorf(y);
        const int x0 = (int)x0f, y0 = (int)y0f;
        const float fx = x - x0f, fy = y - y0f;
        const float wx1 = fx, wx0 = 1.f - fx;
        const float wy1 = fy, wy0 = 1.f - fy;

        #pragma unroll
        for (int c = 0; c < 4; ++c) {
            const int cx = x0 + (c & 1);
            const int cy = y0 + (c >> 1);
            const bool valid = ((unsigned)cx < (unsigned)Wl) & ((unsigned)cy < (unsigned)Hl);
            const int pix = valid ? (St + cy * Wl + cx) : 0;
            const float wc = ((c & 1) ? wx1 : wx0) * ((c >> 1) ? wy1 : wy0) * aw;
            s_aw[t][c] = make_int2((pix * CAMS + cam) * 256 + h * 32,
                                   valid ? __float_as_int(wc) : 0);
        }
        __syncthreads();

        const int ebase = h * 32 + e8 * 4;
        #pragma unroll
        for (int j = 0; j < 4; ++j) {
            #pragma unroll
            for (int c = 0; c < 4; ++c) {
                const int2 awp = s_aw[ebase + j][c];
                const float w = __int_as_float(awp.y);
                const uint4 u = *(const uint4*)(v + awp.x + ch8);
                acc[0] = fmaf(w, bflo(u.x), acc[0]);
                acc[1] = fmaf(w, bfhi(u.x), acc[1]);
                acc[2] = fmaf(w, bflo(u.y), acc[2]);
                acc[3] = fmaf(w, bfhi(u.y), acc[3]);
                acc[4] = fmaf(w, bflo(u.z), acc[4]);
                acc[5] = fmaf(w, bfhi(u.z), acc[5]);
                acc[6] = fmaf(w, bflo(u.w), acc[6]);
                acc[7] = fmaf(w, bfhi(u.w), acc[7]);
            }
        }
        __syncthreads();
    }

    // reduce over the 8 entry-groups: lanes with same (h, ch8), e8 = 0..7
    // lane ids differ by 4, 8, 16 within the 32-lane (h) group
    #pragma unroll
    for (int i = 0; i < 8; ++i) {
        acc[i] += __shfl_xor(acc[i], 4);
        acc[i] += __shfl_xor(acc[i], 8);
        acc[i] += __shfl_xor(acc[i], 16);
    }
    // each thread stores one channel: ch = ch8 + e8
    slots[q * 256 + h * 32 + ch8 + e8] = acc[e8];
}

// ---------------------------------------------------------------------------
extern "C" void kernel_launch(void* const* d_in, const int* in_sizes, int n_in,
                              void* d_out, int out_size, void* d_ws, size_t ws_size,
                              hipStream_t stream) {
    const float* query     = (const float*)d_in[0];
    // d_in[1] = key (unused by reference)
    const float* value     = (const float*)d_in[2];
    const float* query_pos = (const float*)d_in[3];
    const float* refpts    = (const float*)d_in[4];
    const void*  bev_mask  = d_in[5];
    const float* Wv   = (const float*)d_in[8];
    const float* bv   = (const float*)d_in[9];
    const float* Wso  = (const float*)d_in[10];
    const float* bso  = (const float*)d_in[11];
    const float* Waw  = (const float*)d_in[12];
    const float* baw  = (const float*)d_in[13];
    const float* Wout = (const float*)d_in[14];
    const float* bout = (const float*)d_in[15];
    float* out = (float*)d_out;

    // Workspace layout
    ushort* v_ws  = (ushort*)d_ws;                       // MV*256 bf16 = 45.96 MB
    float* off_ws = (float*)(v_ws + (size_t)MV * 256);   // NQ*512 fp32
    float* aw_ws  = off_ws + (size_t)NQ * 512;           // NQ*256
    float* slots  = aw_ws + (size_t)NQ * 256;            // NQ*256
    float* invcnt = slots + (size_t)NQ * 256;            // NQ
    int*   active = (int*)(invcnt + NQ);                 // CAMS*NQ
    int*   flag   = active + (size_t)CAMS * NQ;

    hipLaunchKernelGGL(detect_mask_fmt, dim3(1), dim3(256), 0, stream,
                       (const unsigned*)bev_mask, flag);
    hipLaunchKernelGGL(mask_kernel, dim3((NQ + 255) / 256), dim3(256), 0, stream,
                       bev_mask, flag, active, invcnt);

    // q-projections (cam-independent)
    hipLaunchKernelGGL((gemm_mfma<1, 0>), dim3(NQ / 128, 512 / 128), dim3(256), 0, stream,
                       query, query_pos, Wso, 512, bso, nullptr, off_ws, 512, NQ);
    hipLaunchKernelGGL((gemm_mfma<1, 0>), dim3(NQ / 128, 256 / 128), dim3(256), 0, stream,
                       query, query_pos, Waw, 256, baw, nullptr, aw_ws, 256, NQ);
    hipLaunchKernelGGL(softmax_kernel, dim3(NQ * HEADS / 8), dim3(256), 0, stream, aw_ws);

    // v-projection -> bf16
    hipLaunchKernelGGL((gemm_mfma<0, 1>), dim3((MV + 127) / 128, 256 / 128), dim3(256), 0, stream,
                       value, nullptr, Wv, 256, bv, nullptr, v_ws, 256, MV);

    // deformable sampling
    hipLaunchKernelGGL(sample_kernel, dim3(NQ), dim3(256), 0, stream,
                       v_ws, off_ws, aw_ws, refpts, active, slots);

    // out = (slots/count) @ Wout + bout + query
    hipLaunchKernelGGL((gemm_mfma<2, 0>), dim3(NQ / 128, 256 / 128), dim3(256), 0, stream,
                       slots, invcnt, Wout, 256, bout, query, out, 256, NQ);
}

// Round 3
// 443.279 us; speedup vs baseline: 1.4513x; 1.3248x over previous
//
#include <hip/hip_runtime.h>
#include <hip/hip_bf16.h>

// Problem constants (BS=1)
#define CAMS   6
#define NQ     6400
#define EMBED  256
#define HEADS  8
#define LEVELS 4
#define POINTS 8
#define DEPTH  4
#define DH     32
#define FLEN   14960
#define MV     (FLEN * CAMS)   // 89760 rows for v-projection

__constant__ int c_LW[4] = {176, 88, 44, 22};
__constant__ int c_LH[4] = {64, 32, 16, 8};
__constant__ int c_LS[4] = {0, 11264, 14080, 14784};

typedef __bf16 bf16x8 __attribute__((ext_vector_type(8)));
typedef float  f32x4  __attribute__((ext_vector_type(4)));

__device__ __forceinline__ ushort f2bf(float x) {
    __hip_bfloat16 h = __float2bfloat16(x);
    return *(ushort*)&h;
}
__device__ __forceinline__ float bflo(unsigned u) { return __uint_as_float(u << 16); }
__device__ __forceinline__ float bfhi(unsigned u) { return __uint_as_float(u & 0xffff0000u); }

// ---------------------------------------------------------------------------
// bev_mask format detection (int32 vs raw bool bytes), 64 blocks + atomicOr.
// flag must be zeroed (hipMemsetAsync) before launch.
// ---------------------------------------------------------------------------
__global__ void detect_mask_fmt(const unsigned* __restrict__ bm, int* __restrict__ flag) {
    int i = blockIdx.x * blockDim.x + threadIdx.x;
    const int total = (CAMS * NQ * DEPTH) / 4;
    unsigned acc = 0;
    for (; i < total; i += gridDim.x * blockDim.x) acc |= bm[i];
    if (acc & 0xFFFFFF00u) atomicOr(flag, 1);
}

// actmask[q] = bitmask of active cams; invcnt[q] = 1/max(#active,1)
__global__ void mask_kernel(const void* __restrict__ bm, const int* __restrict__ flag,
                            int* __restrict__ actmask, float* __restrict__ invcnt) {
    int q = blockIdx.x * blockDim.x + threadIdx.x;
    if (q >= NQ) return;
    int fmt = *flag;
    int cnt = 0, m = 0;
    for (int cam = 0; cam < CAMS; ++cam) {
        int a;
        if (fmt == 1) {
            unsigned w = ((const unsigned*)bm)[cam * NQ + q];
            a = (w != 0u);
        } else {
            int4 v = ((const int4*)bm)[cam * NQ + q];
            a = ((v.x | v.y | v.z | v.w) != 0);
        }
        m |= a << cam;
        cnt += a;
    }
    actmask[q] = m;
    invcnt[q] = 1.0f / (float)(cnt > 0 ? cnt : 1);
}

// ---------------------------------------------------------------------------
// bf16 MFMA GEMM (unchanged from R2 — verified correct)
// ---------------------------------------------------------------------------
#define LSTRIDE 40

template <int MODE, int OUT_BF16>
__launch_bounds__(256)
__global__ void gemm_mfma(const float* __restrict__ A,
                          const float* __restrict__ A2,
                          const float* __restrict__ W, int ldw,
                          const float* __restrict__ bias,
                          const float* __restrict__ resid,
                          void* __restrict__ Cout, int ldc, int M) {
    __shared__ ushort sA[128 * LSTRIDE];
    __shared__ ushort sB[128 * LSTRIDE];
    const int t = threadIdx.x;
    const int wave = t >> 6;
    const int lane = t & 63;
    const int wm = wave & 1, wn = wave >> 1;
    const int lane15 = lane & 15;
    const int laneq = lane >> 4;
    const int row0 = blockIdx.x * 128;
    const int col0 = blockIdx.y * 128;

    f32x4 acc[4][4] = {};

    const int a_m = t >> 3;
    const int a_k = (t & 7) * 4;
    const int b_n = t & 127;
    const int b_k = (t >> 7) * 4;

    for (int k0 = 0; k0 < 256; k0 += 32) {
        #pragma unroll
        for (int p = 0; p < 4; ++p) {
            const int m = a_m + p * 32;
            int gm = row0 + m;
            if (gm >= M) gm = M - 1;
            float4 a4 = *(const float4*)(A + (size_t)gm * 256 + k0 + a_k);
            if (MODE == 1) {
                float4 b4 = *(const float4*)(A2 + (size_t)gm * 256 + k0 + a_k);
                a4.x += b4.x; a4.y += b4.y; a4.z += b4.z; a4.w += b4.w;
            } else if (MODE == 2) {
                const float s = A2[gm];
                a4.x *= s; a4.y *= s; a4.z *= s; a4.w *= s;
            }
            ushort4 u = make_ushort4(f2bf(a4.x), f2bf(a4.y), f2bf(a4.z), f2bf(a4.w));
            *(ushort4*)(&sA[m * LSTRIDE + a_k]) = u;
        }
        #pragma unroll
        for (int p = 0; p < 4; ++p) {
            const int k = b_k + p * 8;
            const float* wp = W + (size_t)(k0 + k) * ldw + col0 + b_n;
            const float w0 = wp[0];
            const float w1 = wp[ldw];
            const float w2 = wp[2 * ldw];
            const float w3 = wp[3 * ldw];
            ushort4 u = make_ushort4(f2bf(w0), f2bf(w1), f2bf(w2), f2bf(w3));
            *(ushort4*)(&sB[b_n * LSTRIDE + k]) = u;
        }
        __syncthreads();

        bf16x8 af[4], bfr[4];
        #pragma unroll
        for (int i = 0; i < 4; ++i) {
            const int m = wm * 64 + i * 16 + lane15;
            af[i] = *(const bf16x8*)(&sA[m * LSTRIDE + laneq * 8]);
            const int n = wn * 64 + i * 16 + lane15;
            bfr[i] = *(const bf16x8*)(&sB[n * LSTRIDE + laneq * 8]);
        }
        #pragma unroll
        for (int i = 0; i < 4; ++i)
            #pragma unroll
            for (int j = 0; j < 4; ++j)
                acc[i][j] = __builtin_amdgcn_mfma_f32_16x16x32_bf16(af[i], bfr[j], acc[i][j], 0, 0, 0);
        __syncthreads();
    }

    #pragma unroll
    for (int j = 0; j < 4; ++j) {
        const int col = col0 + wn * 64 + j * 16 + lane15;
        const float bcol = bias[col];
        #pragma unroll
        for (int i = 0; i < 4; ++i) {
            #pragma unroll
            for (int r = 0; r < 4; ++r) {
                const int row = row0 + wm * 64 + i * 16 + laneq * 4 + r;
                if (row < M) {
                    float v = acc[i][j][r] + bcol;
                    if (MODE == 2) v += resid[(size_t)row * 256 + col];
                    if (OUT_BF16)
                        ((ushort*)Cout)[(size_t)row * ldc + col] = f2bf(v);
                    else
                        ((float*)Cout)[(size_t)row * ldc + col] = v;
                }
            }
        }
    }
}

// ---------------------------------------------------------------------------
// softmax over 32 (l,p) entries per (q,h), in-place, fp32
// ---------------------------------------------------------------------------
__global__ void softmax_kernel(float* __restrict__ aw) {
    const int t = threadIdx.x;
    const int g = blockIdx.x * 8 + (t >> 5);
    const int j = t & 31;
    float v = aw[g * 32 + j];
    float m = v;
    for (int off = 16; off > 0; off >>= 1) m = fmaxf(m, __shfl_xor(m, off, 32));
    float e = expf(v - m);
    float s = e;
    for (int off = 16; off > 0; off >>= 1) s += __shfl_xor(s, off, 32);
    aw[g * 32 + j] = e / s;
}

// ---------------------------------------------------------------------------
// Deformable sampling, v in bf16 — barrier-free, LDS-free.
// One block per query. Thread t = h*32 + e8*4 + ch8idx:
//   handles entries e = e8*4 + j (j=0..3) of head h, channels ch8..ch8+7.
//   All 4 entries share level l = e8>>1, and depth d = j exactly.
// Each thread computes its own coords (4x redundant across ch8idx — cheap),
// issues 16 independent uint4 gathers per active cam, accumulates 8 channels.
// After cam loop: butterfly-reduce over e8 (lanes ^4,^8,^16), store 1 ch each.
// ---------------------------------------------------------------------------
__launch_bounds__(256)
__global__ void sample_kernel(const ushort* __restrict__ v,
                              const float* __restrict__ off_ws,
                              const float* __restrict__ aw_ws,
                              const float* __restrict__ rp,      // (CAMS,NQ,DEPTH,2)
                              const int* __restrict__ actmask,
                              float* __restrict__ slots) {
    const int q = blockIdx.x;
    const int t = threadIdx.x;
    const int h = t >> 5;
    const int e8 = (t >> 2) & 7;
    const int ch8 = (t & 3) * 8;
    const int l = e8 >> 1;
    const int ebase = h * 32 + e8 * 4;

    const int Wl = c_LW[l], Hl = c_LH[l], St = c_LS[l];
    const float fWl = (float)Wl, fHl = (float)Hl;

    // cam-independent per-entry offsets + attention weights (4 entries)
    float offx[4], offy[4], awv[4];
    #pragma unroll
    for (int j = 0; j < 4; ++j) {
        float2 o = *(const float2*)(off_ws + (size_t)q * 512 + (ebase + j) * 2);
        offx[j] = o.x;
        offy[j] = o.y;
        awv[j] = aw_ws[(size_t)q * 256 + ebase + j];
    }

    const int am = actmask[q];   // block-uniform
    float acc[8] = {};

    for (int cam = 0; cam < CAMS; ++cam) {
        if (!((am >> cam) & 1)) continue;   // uniform branch

        const float4 r01 = *(const float4*)(rp + (size_t)cam * (NQ * 8) + q * 8);
        const float4 r23 = *(const float4*)(rp + (size_t)cam * (NQ * 8) + q * 8 + 4);
        const float rx[4] = {r01.x, r01.z, r23.x, r23.z};
        const float ry[4] = {r01.y, r01.w, r23.y, r23.w};

        int   addr[16];
        float wgt[16];
        #pragma unroll
        for (int j = 0; j < 4; ++j) {
            const float x = fmaf(rx[j], fWl, offx[j]) - 0.5f;
            const float y = fmaf(ry[j], fHl, offy[j]) - 0.5f;
            const float x0f = floorf(x), y0f = floorf(y);
            const int x0 = (int)x0f, y0 = (int)y0f;
            const float fx = x - x0f, fy = y - y0f;
            const float wx0 = 1.f - fx, wy0 = 1.f - fy;
            #pragma unroll
            for (int c = 0; c < 4; ++c) {
                const int cx = x0 + (c & 1);
                const int cy = y0 + (c >> 1);
                const bool valid = ((unsigned)cx < (unsigned)Wl) & ((unsigned)cy < (unsigned)Hl);
                const int pix = valid ? (St + cy * Wl + cx) : 0;
                addr[j * 4 + c] = (pix * CAMS + cam) * 256 + h * 32 + ch8;
                wgt[j * 4 + c] = valid
                    ? (((c & 1) ? fx : wx0) * ((c >> 1) ? fy : wy0) * awv[j])
                    : 0.f;
            }
        }
        #pragma unroll
        for (int i = 0; i < 16; ++i) {
            const uint4 u = *(const uint4*)(v + addr[i]);
            const float w = wgt[i];
            acc[0] = fmaf(w, bflo(u.x), acc[0]);
            acc[1] = fmaf(w, bfhi(u.x), acc[1]);
            acc[2] = fmaf(w, bflo(u.y), acc[2]);
            acc[3] = fmaf(w, bfhi(u.y), acc[3]);
            acc[4] = fmaf(w, bflo(u.z), acc[4]);
            acc[5] = fmaf(w, bfhi(u.z), acc[5]);
            acc[6] = fmaf(w, bflo(u.w), acc[6]);
            acc[7] = fmaf(w, bfhi(u.w), acc[7]);
        }
    }

    // reduce over the 8 e8-groups (lane bits 2..4 within each 32-lane h-group)
    #pragma unroll
    for (int i = 0; i < 8; ++i) {
        acc[i] += __shfl_xor(acc[i], 4);
        acc[i] += __shfl_xor(acc[i], 8);
        acc[i] += __shfl_xor(acc[i], 16);
    }
    slots[(size_t)q * 256 + h * 32 + ch8 + e8] = acc[e8];
}

// ---------------------------------------------------------------------------
extern "C" void kernel_launch(void* const* d_in, const int* in_sizes, int n_in,
                              void* d_out, int out_size, void* d_ws, size_t ws_size,
                              hipStream_t stream) {
    const float* query     = (const float*)d_in[0];
    // d_in[1] = key (unused by reference)
    const float* value     = (const float*)d_in[2];
    const float* query_pos = (const float*)d_in[3];
    const float* refpts    = (const float*)d_in[4];
    const void*  bev_mask  = d_in[5];
    const float* Wv   = (const float*)d_in[8];
    const float* bv   = (const float*)d_in[9];
    const float* Wso  = (const float*)d_in[10];
    const float* bso  = (const float*)d_in[11];
    const float* Waw  = (const float*)d_in[12];
    const float* baw  = (const float*)d_in[13];
    const float* Wout = (const float*)d_in[14];
    const float* bout = (const float*)d_in[15];
    float* out = (float*)d_out;

    // Workspace layout
    ushort* v_ws  = (ushort*)d_ws;                       // MV*256 bf16 = 45.96 MB
    float* off_ws = (float*)(v_ws + (size_t)MV * 256);   // NQ*512 fp32
    float* aw_ws  = off_ws + (size_t)NQ * 512;           // NQ*256
    float* slots  = aw_ws + (size_t)NQ * 256;            // NQ*256
    float* invcnt = slots + (size_t)NQ * 256;            // NQ
    int*   actmask = (int*)(invcnt + NQ);                // NQ
    int*   flag   = actmask + NQ;

    hipMemsetAsync(flag, 0, sizeof(int), stream);
    hipLaunchKernelGGL(detect_mask_fmt, dim3(64), dim3(256), 0, stream,
                       (const unsigned*)bev_mask, flag);
    hipLaunchKernelGGL(mask_kernel, dim3((NQ + 255) / 256), dim3(256), 0, stream,
                       bev_mask, flag, actmask, invcnt);

    // q-projections (cam-independent)
    hipLaunchKernelGGL((gemm_mfma<1, 0>), dim3(NQ / 128, 512 / 128), dim3(256), 0, stream,
                       query, query_pos, Wso, 512, bso, nullptr, off_ws, 512, NQ);
    hipLaunchKernelGGL((gemm_mfma<1, 0>), dim3(NQ / 128, 256 / 128), dim3(256), 0, stream,
                       query, query_pos, Waw, 256, baw, nullptr, aw_ws, 256, NQ);
    hipLaunchKernelGGL(softmax_kernel, dim3(NQ * HEADS / 8), dim3(256), 0, stream, aw_ws);

    // v-projection -> bf16
    hipLaunchKernelGGL((gemm_mfma<0, 1>), dim3((MV + 127) / 128, 256 / 128), dim3(256), 0, stream,
                       value, nullptr, Wv, 256, bv, nullptr, v_ws, 256, MV);

    // deformable sampling (barrier-free)
    hipLaunchKernelGGL(sample_kernel, dim3(NQ), dim3(256), 0, stream,
                       v_ws, off_ws, aw_ws, refpts, actmask, slots);

    // out = (slots/count) @ Wout + bout + query
    hipLaunchKernelGGL((gemm_mfma<2, 0>), dim3(NQ / 128, 256 / 128), dim3(256), 0, stream,
                       slots, invcnt, Wout, 256, bout, query, out, 256, NQ);
}